// Round 12
// baseline (10.733 us; speedup 1.0000x reference)
//
#include <hip/hip_runtime.h>

#define HW 56
#define PLANE 3136     // 56*56
#define CH 64          // channels after pair-sum
#define CI 32          // output channels
#define NI 4           // output channels per block
#define NQ 8           // channel groups per block (CQ channels each)
#define CQ 8           // channels per group
#define PX 32          // pixels per block

// Split-channel kernel v2: block = 256 = 32 pixels x 8 channel-groups.
// Each thread computes an 8-channel partial for 4 output channels at 1 pixel;
// LDS reduce across the 8 groups; 128 threads store with fused roll.
// grid = (98, 8): 98*32 = 3136 pixels exact; 784 blocks = 3136 waves.
__global__ __launch_bounds__(256) void convshift_kernel(
    const float* __restrict__ x, const float* __restrict__ Wt, float* __restrict__ out)
{
    __shared__ float sW[NI * CH * 3];     // 768 floats
    __shared__ float red[NQ][NI][PX];     // 4 KB partials

    const int i0  = blockIdx.y * NI;
    const int tid = threadIdx.x;
    #pragma unroll
    for (int t = tid; t < NI * CH * 3; t += 256)
        sW[t] = Wt[i0 * (CH * 3) + t];
    __syncthreads();

    const int px = tid & (PX - 1);        // pixel lane
    const int q  = tid >> 5;              // channel group 0..7
    const int p  = blockIdx.x * PX + px;  // 0..3135, exact cover
    const int h  = p / HW;
    const int w  = p - h * HW;

    const bool v0 = (h > 0), v2 = (h < HW - 1);
    const int hm = v0 ? h - 1 : 0;        // clamped rows; masked before reduce
    const int hp = v2 ? h + 1 : HW - 1;

    const int c0 = q * CQ;
    const float* __restrict__ xa = x + c0 * PLANE + w;          // first-half channels
    const float* __restrict__ xb = x + (CH + c0) * PLANE + w;   // second-half channels
    const int r0 = hm * HW, r1 = h * HW, r2 = hp * HW;

    // stage all 8 channels x 3 rows x 2 halves = 48 independent loads (max MLP)
    float A0[CQ], A1[CQ], A2[CQ], B0[CQ], B1[CQ], B2[CQ];
    #pragma unroll
    for (int j = 0; j < CQ; ++j) {
        const int o = j * PLANE;
        A0[j] = xa[o + r0]; A1[j] = xa[o + r1]; A2[j] = xa[o + r2];
        B0[j] = xb[o + r0]; B1[j] = xb[o + r1]; B2[j] = xb[o + r2];
    }

    float acc[NI][3];
    #pragma unroll
    for (int ii = 0; ii < NI; ++ii) { acc[ii][0] = 0.f; acc[ii][1] = 0.f; acc[ii][2] = 0.f; }

    #pragma unroll
    for (int j = 0; j < CQ; ++j) {
        const int ca = c0 + j;                    // absolute channel for weights
        const float s0 = A0[j] + B0[j];           // pair-sum once
        const float s1 = A1[j] + B1[j];
        const float s2 = A2[j] + B2[j];
        #pragma unroll
        for (int ii = 0; ii < NI; ++ii) {
            acc[ii][0] += s0 * sW[ii * (CH * 3) + ca * 3 + 0];
            acc[ii][1] += s1 * sW[ii * (CH * 3) + ca * 3 + 1];
            acc[ii][2] += s2 * sW[ii * (CH * 3) + ca * 3 + 2];
        }
    }

    // mask boundary taps, deposit partials
    #pragma unroll
    for (int ii = 0; ii < NI; ++ii) {
        float r = acc[ii][1];
        if (v0) r += acc[ii][0];
        if (v2) r += acc[ii][2];
        red[q][ii][px] = r;
    }
    __syncthreads();

    // 128 threads: sum the 8 group-partials (tree) and store with fused roll
    if (tid < NI * PX) {
        const int ii  = tid >> 5;
        const int px2 = tid & (PX - 1);
        const float s = ((red[0][ii][px2] + red[1][ii][px2])
                       + (red[2][ii][px2] + red[3][ii][px2]))
                      + ((red[4][ii][px2] + red[5][ii][px2])
                       + (red[6][ii][px2] + red[7][ii][px2]));
        const int p2 = blockIdx.x * PX + px2;
        const int h2 = p2 / HW;
        const int w2 = p2 - h2 * HW;
        int wst = w2 + 1; if (wst == HW) wst = 0;   // fuse jnp.roll(+1, axis=w)
        out[(i0 + ii) * PLANE + h2 * HW + wst] = s;
    }
}

extern "C" void kernel_launch(void* const* d_in, const int* in_sizes, int n_in,
                              void* d_out, int out_size, void* d_ws, size_t ws_size,
                              hipStream_t stream) {
    const float* x  = (const float*)d_in[0];   // (1,128,56,56) f32
    const float* Wt = (const float*)d_in[1];   // (32,64,3) f32
    float* out = (float*)d_out;                // (1,32,56,56) f32

    dim3 grid(98, CI / NI), block(256);
    hipLaunchKernelGGL(convshift_kernel, grid, block, 0, stream, x, Wt, out);
}

// Round 13
// 10.242 us; speedup vs baseline: 1.0480x; 1.0480x over previous
//
#include <hip/hip_runtime.h>

#define HW 56
#define PLANE 3136     // 56*56
#define CH 64          // channels after pair-sum
#define CI 32          // output channels
#define NI 2           // output channels per block (and per final store thread)
#define NQ 4           // channel quarters (one wave each)
#define CQ (CH/NQ)     // 16 channels per quarter

// Split-channel kernel: block = 256 = 64 pixels x 4 channel-quarters.
// Each wave computes a 16-channel partial for 64 pixels; LDS reduce; store.
// grid = (49, 16): 49*64 = 3136 pixels exact, 16 i-groups x NI=2. 3136 waves.
// Best-measured configuration (R11: 10.43 us). Kernel ~1.5-2 us vs ~8.5-9 us
// single-launch graph floor; traffic-halving (R12) and vectorization (R10)
// both failed to beat this — TLP (3 waves/SIMD) is the binding resource.
__global__ __launch_bounds__(256) void convshift_kernel(
    const float* __restrict__ x, const float* __restrict__ Wt, float* __restrict__ out)
{
    __shared__ float sW[NI * CH * 3];    // 384 floats
    __shared__ float red[NQ][NI][64];    // 2 KB partial sums

    const int i0  = blockIdx.y * NI;
    const int tid = threadIdx.x;
    #pragma unroll
    for (int t = tid; t < NI * CH * 3; t += 256)
        sW[t] = Wt[i0 * (CH * 3) + t];
    __syncthreads();

    const int px = tid & 63;             // pixel lane within block
    const int q  = tid >> 6;             // channel quarter = wave id
    const int p  = blockIdx.x * 64 + px; // 0..3135, exact cover
    const int h  = p / HW;
    const int w  = p - h * HW;

    const bool v0 = (h > 0), v2 = (h < HW - 1);
    const int hm = v0 ? h - 1 : 0;       // clamped rows; masked before reduction
    const int hp = v2 ? h + 1 : HW - 1;

    const int c0 = q * CQ;
    const float* __restrict__ xa = x + c0 * PLANE + w;          // first-half channels
    const float* __restrict__ xb = x + (CH + c0) * PLANE + w;   // second-half channels
    const int r0 = hm * HW, r1 = h * HW, r2 = hp * HW;

    float acc[NI][3];
    #pragma unroll
    for (int ii = 0; ii < NI; ++ii) { acc[ii][0] = 0.f; acc[ii][1] = 0.f; acc[ii][2] = 0.f; }

    // double-buffered register staging: 8 channels x 3 rows x 2 halves in flight
    float A0[2][8], A1[2][8], A2[2][8], B0[2][8], B1[2][8], B2[2][8];

    #pragma unroll
    for (int j = 0; j < 8; ++j) {
        const int o = j * PLANE;
        A0[0][j] = xa[o + r0]; A1[0][j] = xa[o + r1]; A2[0][j] = xa[o + r2];
        B0[0][j] = xb[o + r0]; B1[0][j] = xb[o + r1]; B2[0][j] = xb[o + r2];
    }

    #pragma unroll
    for (int chk = 0; chk < 2; ++chk) {
        const int cur = chk & 1, nxt = cur ^ 1;
        if (chk < 1) {
            #pragma unroll
            for (int j = 0; j < 8; ++j) {
                const int o = (8 + j) * PLANE;
                A0[nxt][j] = xa[o + r0]; A1[nxt][j] = xa[o + r1]; A2[nxt][j] = xa[o + r2];
                B0[nxt][j] = xb[o + r0]; B1[nxt][j] = xb[o + r1]; B2[nxt][j] = xb[o + r2];
            }
        }
        #pragma unroll
        for (int j = 0; j < 8; ++j) {
            const int ca = c0 + chk * 8 + j;          // absolute channel for weights
            const float s0 = A0[cur][j] + B0[cur][j]; // pair-sum once
            const float s1 = A1[cur][j] + B1[cur][j];
            const float s2 = A2[cur][j] + B2[cur][j];
            #pragma unroll
            for (int ii = 0; ii < NI; ++ii) {
                acc[ii][0] += s0 * sW[ii * (CH * 3) + ca * 3 + 0];
                acc[ii][1] += s1 * sW[ii * (CH * 3) + ca * 3 + 1];
                acc[ii][2] += s2 * sW[ii * (CH * 3) + ca * 3 + 2];
            }
        }
    }

    // mask boundary taps, deposit partials
    #pragma unroll
    for (int ii = 0; ii < NI; ++ii) {
        float r = acc[ii][1];
        if (v0) r += acc[ii][0];
        if (v2) r += acc[ii][2];
        red[q][ii][px] = r;
    }
    __syncthreads();

    // 128 threads: sum the 4 quarter-partials and store with fused roll
    if (tid < NI * 64) {
        const int ii  = tid >> 6;
        const int px2 = tid & 63;
        const float s = (red[0][ii][px2] + red[1][ii][px2])
                      + (red[2][ii][px2] + red[3][ii][px2]);
        const int p2 = blockIdx.x * 64 + px2;
        const int h2 = p2 / HW;
        const int w2 = p2 - h2 * HW;
        int wst = w2 + 1; if (wst == HW) wst = 0;   // fuse jnp.roll(+1, axis=w)
        out[(i0 + ii) * PLANE + h2 * HW + wst] = s;
    }
}

extern "C" void kernel_launch(void* const* d_in, const int* in_sizes, int n_in,
                              void* d_out, int out_size, void* d_ws, size_t ws_size,
                              hipStream_t stream) {
    const float* x  = (const float*)d_in[0];   // (1,128,56,56) f32
    const float* Wt = (const float*)d_in[1];   // (32,64,3) f32
    float* out = (float*)d_out;                // (1,32,56,56) f32

    dim3 grid(49, CI / NI), block(256);
    hipLaunchKernelGGL(convshift_kernel, grid, block, 0, stream, x, Wt, out);
}